// Round 7
// baseline (405.991 us; speedup 1.0000x reference)
//
#include <hip/hip_runtime.h>
#include <hip/hip_bf16.h>

// EdgePredictorGNN: 2-layer GCN + edge MLP.
// N=50000 nodes, in_c=128, hid=64, out_c=16, E=800000 edges.
// Round-7: float4 gather agg (4 rows in flight/wave), layer-2 GEMM fused into
// agg1 epilogue (h1 never materialized), nt stores for out, wave-parallel scan2.

#define IN_C 128
#define HID 64
#define OUT_C 16

typedef float f32x4 __attribute__((ext_vector_type(4)));

__device__ __forceinline__ float rlanef(float v, int l) {
    return __uint_as_float(__builtin_amdgcn_readlane(__float_as_uint(v), l));
}

__device__ __forceinline__ void nt_store4(float* p, float4 v) {
    f32x4 x = {v.x, v.y, v.z, v.w};
    __builtin_nontemporal_store(x, (f32x4*)p);
}

// ---------------- CSR build ----------------

__global__ void k_init_cnt(int* __restrict__ cnt, int n) {
    int i = blockIdx.x * blockDim.x + threadIdx.x;
    if (i < n) cnt[i] = 0;
}

__global__ void k_count(const int* __restrict__ ei, int* __restrict__ cnt, int e) {
    int i = blockIdx.x * blockDim.x + threadIdx.x;
    if (i < e) atomicAdd(&cnt[ei[e + i]], 1);   // dst = ei[1][i]
}

__global__ __launch_bounds__(1024) void k_scan1(const int* __restrict__ cnt,
                                                int* __restrict__ tmp,
                                                int* __restrict__ bsum, int n) {
    __shared__ int s[1024];
    int i = blockIdx.x * 1024 + threadIdx.x;
    int v = (i < n) ? cnt[i] : 0;
    s[threadIdx.x] = v;
    __syncthreads();
    for (int off = 1; off < 1024; off <<= 1) {
        int add = (threadIdx.x >= off) ? s[threadIdx.x - off] : 0;
        __syncthreads();
        s[threadIdx.x] += add;
        __syncthreads();
    }
    if (i < n) tmp[i] = s[threadIdx.x];
    if (threadIdx.x == 1023) bsum[blockIdx.x] = s[1023];
}

// wave-parallel exclusive scan of up to 64 block sums
__global__ __launch_bounds__(64) void k_scan2(int* __restrict__ bsum, int nb) {
    int lane = threadIdx.x;
    int v = (lane < nb) ? bsum[lane] : 0;
    int orig = v;
    for (int off = 1; off < 64; off <<= 1) {
        int t = __shfl_up(v, off, 64);
        if (lane >= off) v += t;
    }
    if (lane < nb) bsum[lane] = v - orig;   // exclusive prefix
}

__global__ void k_scan3(const int* __restrict__ cnt, const int* __restrict__ tmp,
                        const int* __restrict__ bsum, int* __restrict__ rowptr,
                        int* __restrict__ cur, float* __restrict__ dinv, int n, int e) {
    int i = blockIdx.x * blockDim.x + threadIdx.x;
    if (i < n) {
        int excl = tmp[i] - cnt[i] + bsum[i >> 10];
        rowptr[i] = excl;
        cur[i] = excl;
        dinv[i] = 1.0f / sqrtf((float)(cnt[i] + 1));  // +1 self loop
        if (i == 0) rowptr[n] = e;
    }
}

__global__ void k_scatter(const int* __restrict__ ei, int* __restrict__ cur,
                          int* __restrict__ csrc, int2* __restrict__ cde, int e) {
    int i = blockIdx.x * blockDim.x + threadIdx.x;
    if (i < e) {
        int s = ei[i];
        int d = ei[e + i];
        int p = atomicAdd(&cur[d], 1);
        csrc[p] = s;
        cde[p] = make_int2(d, i);
    }
}

// ---------------- node GEMM: T = (A @ W) * dinv[row]  (W is [K,64]) ----------------

template <int K>
__global__ __launch_bounds__(256) void k_gemm_node(const float* __restrict__ A,
                                                   const float* __restrict__ W,
                                                   const float* __restrict__ dinv,
                                                   float* __restrict__ T,
                                                   int n, int npw) {
    int lane = threadIdx.x & 63;
    int w = threadIdx.x >> 6;
    float wr[K];
#pragma unroll
    for (int k = 0; k < K; ++k) wr[k] = W[k * 64 + lane];
    int gw = blockIdx.x * 4 + w;
    int n0 = gw * npw;
    int n1 = n0 + npw; if (n1 > n) n1 = n;
#pragma unroll 1
    for (int i = n0; i < n1; ++i) {
        float a0 = A[(size_t)i * K + lane];
        float a1 = 0.f;
        if (K == 128) a1 = A[(size_t)i * K + 64 + lane];
        float acc = 0.f;
#pragma unroll
        for (int k = 0; k < 64; ++k) acc = fmaf(rlanef(a0, k), wr[k], acc);
        if (K == 128) {
#pragma unroll
            for (int k = 0; k < 64; ++k) acc = fmaf(rlanef(a1, k), wr[64 + k], acc);
        }
        T[(size_t)i * 64 + lane] = acc * dinv[i];
    }
}

// uv GEMM: ut = h @ Wm1[0:64], vt = h @ Wm1[64:128] + bm1   (h = h2, [n][64])
__global__ __launch_bounds__(256) void k_gemm_uv(const float* __restrict__ Hm,
                                                 const float* __restrict__ Wm1,
                                                 const float* __restrict__ bm1,
                                                 float* __restrict__ ut,
                                                 float* __restrict__ vt,
                                                 int n, int npw) {
    int lane = threadIdx.x & 63;
    int w = threadIdx.x >> 6;
    float wu[64], wv[64];
#pragma unroll
    for (int k = 0; k < 64; ++k) wu[k] = Wm1[k * 64 + lane];
#pragma unroll
    for (int k = 0; k < 64; ++k) wv[k] = Wm1[(64 + k) * 64 + lane];
    float bv = bm1[lane];
    int gw = blockIdx.x * 4 + w;
    int n0 = gw * npw;
    int n1 = n0 + npw; if (n1 > n) n1 = n;
#pragma unroll 1
    for (int i = n0; i < n1; ++i) {
        float a0 = Hm[(size_t)i * 64 + lane];
        float au = 0.f, av = 0.f;
#pragma unroll
        for (int k = 0; k < 64; ++k) {
            float hb = rlanef(a0, k);
            au = fmaf(hb, wu[k], au);
            av = fmaf(hb, wv[k], av);
        }
        ut[(size_t)i * 64 + lane] = au;
        vt[(size_t)i * 64 + lane] = av + bv;
    }
}

// ---------------- GCN aggregation, float4 gather core ----------------
// lane = (g = lane>>4, c4 = lane&15). 4 neighbor rows in flight per iter,
// each as 16 lanes x float4 (full 256-B row). Cross-group shfl_xor reduce.

__device__ __forceinline__ float4 agg_gather(const float* __restrict__ T,
                                             const int* __restrict__ rowptr,
                                             const int* __restrict__ csrc,
                                             float dn, float4 b4,
                                             int nid, int g, int c4) {
    float4 acc = make_float4(0.f, 0.f, 0.f, 0.f);
    if (g == 0) {
        acc = *(const float4*)(T + (size_t)nid * 64 + 4 * c4);   // self loop
    }
    int r0 = rowptr[nid], r1 = rowptr[nid + 1];
#pragma unroll 1
    for (int p = r0 + g; p < r1; p += 4) {
        int s = csrc[p];
        float4 t = *(const float4*)(T + (size_t)s * 64 + 4 * c4);
        acc.x += t.x; acc.y += t.y; acc.z += t.z; acc.w += t.w;
    }
    acc.x += __shfl_xor(acc.x, 16, 64); acc.y += __shfl_xor(acc.y, 16, 64);
    acc.z += __shfl_xor(acc.z, 16, 64); acc.w += __shfl_xor(acc.w, 16, 64);
    acc.x += __shfl_xor(acc.x, 32, 64); acc.y += __shfl_xor(acc.y, 32, 64);
    acc.z += __shfl_xor(acc.z, 32, 64); acc.w += __shfl_xor(acc.w, 32, 64);
    float4 h;
    h.x = fmaxf(fmaf(dn, acc.x, b4.x), 0.f);
    h.y = fmaxf(fmaf(dn, acc.y, b4.y), 0.f);
    h.z = fmaxf(fmaf(dn, acc.z, b4.z), 0.f);
    h.w = fmaxf(fmaf(dn, acc.w, b4.w), 0.f);
    return h;
}

// layer-1 agg with fused layer-2 GEMM epilogue: T2 = (h1 @ W2) * dinv, h1 in regs only
__global__ __launch_bounds__(256) void k_agg_l1(const float* __restrict__ T,
                                                const int* __restrict__ rowptr,
                                                const int* __restrict__ csrc,
                                                const float* __restrict__ dinv,
                                                const float* __restrict__ bias,
                                                const float* __restrict__ W2,
                                                float* __restrict__ T2,
                                                int n, int npw) {
    int lane = threadIdx.x & 63;
    int w = threadIdx.x >> 6;
    int g = lane >> 4, c4 = lane & 15;
    float wr[64];
#pragma unroll
    for (int k = 0; k < 64; ++k) wr[k] = W2[k * 64 + lane];
    float4 b4 = ((const float4*)bias)[c4];
    int gw = blockIdx.x * 4 + w;
    int n0 = gw * npw;
    int n1 = n0 + npw; if (n1 > n) n1 = n;
#pragma unroll 1
    for (int nid = n0; nid < n1; ++nid) {
        float dn = dinv[nid];
        float4 h = agg_gather(T, rowptr, csrc, dn, b4, nid, g, c4);
        float acc2 = 0.f;
#pragma unroll
        for (int q = 0; q < 16; ++q) {
            acc2 = fmaf(rlanef(h.x, q), wr[4 * q + 0], acc2);
            acc2 = fmaf(rlanef(h.y, q), wr[4 * q + 1], acc2);
            acc2 = fmaf(rlanef(h.z, q), wr[4 * q + 2], acc2);
            acc2 = fmaf(rlanef(h.w, q), wr[4 * q + 3], acc2);
        }
        T2[(size_t)nid * 64 + lane] = acc2 * dn;
    }
}

// layer-2 agg: writes h2
__global__ __launch_bounds__(256) void k_agg_l2(const float* __restrict__ T,
                                                const int* __restrict__ rowptr,
                                                const int* __restrict__ csrc,
                                                const float* __restrict__ dinv,
                                                const float* __restrict__ bias,
                                                float* __restrict__ H,
                                                int n, int npw) {
    int lane = threadIdx.x & 63;
    int w = threadIdx.x >> 6;
    int g = lane >> 4, c4 = lane & 15;
    float4 b4 = ((const float4*)bias)[c4];
    int gw = blockIdx.x * 4 + w;
    int n0 = gw * npw;
    int n1 = n0 + npw; if (n1 > n) n1 = n;
#pragma unroll 1
    for (int nid = n0; nid < n1; ++nid) {
        float dn = dinv[nid];
        float4 h = agg_gather(T, rowptr, csrc, dn, b4, nid, g, c4);
        if (g == 0) *(float4*)(H + (size_t)nid * 64 + 4 * c4) = h;
    }
}

// ---------------- edge MLP (CSR order, u/v precomputed) ----------------

#define RELUADD4(zq, uq, vq) \
    zq.x = fmaxf(uq.x + vq.x, 0.f); zq.y = fmaxf(uq.y + vq.y, 0.f); \
    zq.z = fmaxf(uq.z + vq.z, 0.f); zq.w = fmaxf(uq.w + vq.w, 0.f);

#define S2Q(zs, j) { \
    const float* w2 = Wm2 + (size_t)(j) * 16; \
    o0.x = fmaf(zs, w2[0],  o0.x);  o0.y = fmaf(zs, w2[1],  o0.y); \
    o0.z = fmaf(zs, w2[2],  o0.z);  o0.w = fmaf(zs, w2[3],  o0.w); \
    o1.x = fmaf(zs, w2[4],  o1.x);  o1.y = fmaf(zs, w2[5],  o1.y); \
    o1.z = fmaf(zs, w2[6],  o1.z);  o1.w = fmaf(zs, w2[7],  o1.w); \
    o2.x = fmaf(zs, w2[8],  o2.x);  o2.y = fmaf(zs, w2[9],  o2.y); \
    o2.z = fmaf(zs, w2[10], o2.z);  o2.w = fmaf(zs, w2[11], o2.w); \
    o3.x = fmaf(zs, w2[12], o3.x);  o3.y = fmaf(zs, w2[13], o3.y); \
    o3.z = fmaf(zs, w2[14], o3.z);  o3.w = fmaf(zs, w2[15], o3.w); }

__global__ __launch_bounds__(256, 4) void k_mlp(const float* __restrict__ ut,
                                                const float* __restrict__ vt,
                                                const int* __restrict__ csrc,
                                                const int2* __restrict__ cde,
                                                const float* __restrict__ Wm2,  // [64][16]
                                                const float* __restrict__ bm2,
                                                float* __restrict__ out,
                                                int e) {
    int p = blockIdx.x * 256 + threadIdx.x;
    bool ok = p < e;
    int idx = ok ? p : 0;
    int r = __builtin_nontemporal_load(&csrc[idx]);
    long long cv = __builtin_nontemporal_load((const long long*)(cde + idx));
    int c  = (int)(cv & 0xffffffffll);
    int eo = (int)(cv >> 32);

    const float4* uq = (const float4*)(ut + (size_t)r * 64);
    const float4* vq = (const float4*)(vt + (size_t)c * 64);

    float4 u0 = uq[0],  u1 = uq[1],  u2 = uq[2],  u3 = uq[3];
    float4 u4 = uq[4],  u5 = uq[5],  u6 = uq[6],  u7 = uq[7];
    float4 u8 = uq[8],  u9 = uq[9],  u10 = uq[10], u11 = uq[11];
    float4 u12 = uq[12], u13 = uq[13], u14 = uq[14], u15 = uq[15];
    float4 v0 = vq[0],  v1 = vq[1],  v2 = vq[2],  v3 = vq[3];
    float4 v4 = vq[4],  v5 = vq[5],  v6 = vq[6],  v7 = vq[7];
    float4 v8 = vq[8],  v9 = vq[9],  v10 = vq[10], v11 = vq[11];
    float4 v12 = vq[12], v13 = vq[13], v14 = vq[14], v15 = vq[15];

    float4 z0, z1, z2, z3, z4, z5, z6, z7, z8, z9, z10, z11, z12, z13, z14, z15;
    RELUADD4(z0, u0, v0)    RELUADD4(z1, u1, v1)    RELUADD4(z2, u2, v2)    RELUADD4(z3, u3, v3)
    RELUADD4(z4, u4, v4)    RELUADD4(z5, u5, v5)    RELUADD4(z6, u6, v6)    RELUADD4(z7, u7, v7)
    RELUADD4(z8, u8, v8)    RELUADD4(z9, u9, v9)    RELUADD4(z10, u10, v10) RELUADD4(z11, u11, v11)
    RELUADD4(z12, u12, v12) RELUADD4(z13, u13, v13) RELUADD4(z14, u14, v14) RELUADD4(z15, u15, v15)

    const float4* b2q = (const float4*)bm2;
    float4 o0 = b2q[0], o1 = b2q[1], o2 = b2q[2], o3 = b2q[3];

    S2Q(z0.x, 0)   S2Q(z0.y, 1)   S2Q(z0.z, 2)   S2Q(z0.w, 3)
    S2Q(z1.x, 4)   S2Q(z1.y, 5)   S2Q(z1.z, 6)   S2Q(z1.w, 7)
    S2Q(z2.x, 8)   S2Q(z2.y, 9)   S2Q(z2.z, 10)  S2Q(z2.w, 11)
    S2Q(z3.x, 12)  S2Q(z3.y, 13)  S2Q(z3.z, 14)  S2Q(z3.w, 15)
    S2Q(z4.x, 16)  S2Q(z4.y, 17)  S2Q(z4.z, 18)  S2Q(z4.w, 19)
    S2Q(z5.x, 20)  S2Q(z5.y, 21)  S2Q(z5.z, 22)  S2Q(z5.w, 23)
    S2Q(z6.x, 24)  S2Q(z6.y, 25)  S2Q(z6.z, 26)  S2Q(z6.w, 27)
    S2Q(z7.x, 28)  S2Q(z7.y, 29)  S2Q(z7.z, 30)  S2Q(z7.w, 31)
    S2Q(z8.x, 32)  S2Q(z8.y, 33)  S2Q(z8.z, 34)  S2Q(z8.w, 35)
    S2Q(z9.x, 36)  S2Q(z9.y, 37)  S2Q(z9.z, 38)  S2Q(z9.w, 39)
    S2Q(z10.x, 40) S2Q(z10.y, 41) S2Q(z10.z, 42) S2Q(z10.w, 43)
    S2Q(z11.x, 44) S2Q(z11.y, 45) S2Q(z11.z, 46) S2Q(z11.w, 47)
    S2Q(z12.x, 48) S2Q(z12.y, 49) S2Q(z12.z, 50) S2Q(z12.w, 51)
    S2Q(z13.x, 52) S2Q(z13.y, 53) S2Q(z13.z, 54) S2Q(z13.w, 55)
    S2Q(z14.x, 56) S2Q(z14.y, 57) S2Q(z14.z, 58) S2Q(z14.w, 59)
    S2Q(z15.x, 60) S2Q(z15.y, 61) S2Q(z15.z, 62) S2Q(z15.w, 63)

    if (ok) {
        float* op = out + (size_t)eo * 16;
        nt_store4(op + 0,  o0);
        nt_store4(op + 4,  o1);
        nt_store4(op + 8,  o2);
        nt_store4(op + 12, o3);
    }
}

// ---------------- launch ----------------

extern "C" void kernel_launch(void* const* d_in, const int* in_sizes, int n_in,
                              void* d_out, int out_size, void* d_ws, size_t ws_size,
                              hipStream_t stream) {
    const float* x   = (const float*)d_in[0];
    const int*   ei  = (const int*)d_in[1];
    const float* W1  = (const float*)d_in[2];
    const float* b1  = (const float*)d_in[3];
    const float* W2  = (const float*)d_in[4];
    const float* b2  = (const float*)d_in[5];
    const float* Wm1 = (const float*)d_in[6];
    const float* bm1 = (const float*)d_in[7];
    const float* Wm2 = (const float*)d_in[8];
    const float* bm2 = (const float*)d_in[9];
    float* out = (float*)d_out;

    int n = in_sizes[0] / IN_C;       // 50000
    int e = in_sizes[1] / 2;          // 800000

    // workspace layout (16B-aligned chunks)
    char* w = (char*)d_ws;
    int* cnt    = (int*)w;                 w += (size_t)n * 4;
    int* tmp    = (int*)w;                 w += (size_t)n * 4;
    int* bsum   = (int*)w;                 w += 256 * 4;
    int* rowptr = (int*)w;                 w += (size_t)(n + 4) * 4;
    int* cur    = (int*)w;                 w += (size_t)n * 4;
    float* dinv = (float*)w;               w += (size_t)n * 4;
    int* csrc   = (int*)w;                 w += (size_t)e * 4;
    int2* cde   = (int2*)w;                w += (size_t)e * 8;
    float* t1   = (float*)w;               w += (size_t)n * HID * 4;
    float* t2   = (float*)w;               w += (size_t)n * HID * 4;
    float* h2   = (float*)w;               w += (size_t)n * HID * 4;
    float* ut   = t1;   // reuse: t1 dead after agg_l1
    float* vt   = t2;   // reuse: t2 dead after agg_l2

    int nb_n256 = (n + 255) / 256;
    int nb_e256 = (e + 255) / 256;
    int nb_scan = (n + 1023) / 1024;

    k_init_cnt<<<nb_n256, 256, 0, stream>>>(cnt, n);
    k_count<<<nb_e256, 256, 0, stream>>>(ei, cnt, e);
    k_scan1<<<nb_scan, 1024, 0, stream>>>(cnt, tmp, bsum, n);
    k_scan2<<<1, 64, 0, stream>>>(bsum, nb_scan);
    k_scan3<<<nb_n256, 256, 0, stream>>>(cnt, tmp, bsum, rowptr, cur, dinv, n, e);
    k_scatter<<<nb_e256, 256, 0, stream>>>(ei, cur, csrc, cde, e);

    const int NPW = 8;                               // nodes per wave (gemm)
    int nwaves = (n + NPW - 1) / NPW;
    int nb_gemm = (nwaves + 3) / 4;
    const int NPB = 8;                               // nodes per wave (agg)
    int nb_agg = (n + 4 * NPB - 1) / (4 * NPB);

    // layer 1 transform
    k_gemm_node<IN_C><<<nb_gemm, 256, 0, stream>>>(x, W1, dinv, t1, n, NPW);
    // layer-1 agg + fused layer-2 transform
    k_agg_l1<<<nb_agg, 256, 0, stream>>>(t1, rowptr, csrc, dinv, b1, W2, t2, n, NPB);
    // layer-2 agg
    k_agg_l2<<<nb_agg, 256, 0, stream>>>(t2, rowptr, csrc, dinv, b2, h2, n, NPB);
    // per-node u/v for the edge MLP
    k_gemm_uv<<<nb_gemm, 256, 0, stream>>>(h2, Wm1, bm1, ut, vt, n, NPW);
    // edge MLP in CSR order
    int nb_mlp = (e + 255) / 256;
    k_mlp<<<nb_mlp, 256, 0, stream>>>(ut, vt, csrc, cde, Wm2, bm2, out, e);
}

// Round 8
// 327.666 us; speedup vs baseline: 1.2390x; 1.2390x over previous
//
#include <hip/hip_runtime.h>
#include <hip/hip_bf16.h>

// EdgePredictorGNN: 2-layer GCN + edge MLP.
// N=50000 nodes, in_c=128, hid=64, out_c=16, E=800000 edges.
// Round-8: round-7 structure (float4 agg, fused l2-GEMM, int2 cde) with the
// nontemporal experiment REVERTED (nt stores on scattered 64B chunks defeated
// L2 write-merging: WRITE 50->128 MB, k_mlp 65->143 us).

#define IN_C 128
#define HID 64
#define OUT_C 16

__device__ __forceinline__ float rlanef(float v, int l) {
    return __uint_as_float(__builtin_amdgcn_readlane(__float_as_uint(v), l));
}

// ---------------- CSR build ----------------

__global__ void k_init_cnt(int* __restrict__ cnt, int n) {
    int i = blockIdx.x * blockDim.x + threadIdx.x;
    if (i < n) cnt[i] = 0;
}

__global__ void k_count(const int* __restrict__ ei, int* __restrict__ cnt, int e) {
    int i = blockIdx.x * blockDim.x + threadIdx.x;
    if (i < e) atomicAdd(&cnt[ei[e + i]], 1);   // dst = ei[1][i]
}

__global__ __launch_bounds__(1024) void k_scan1(const int* __restrict__ cnt,
                                                int* __restrict__ tmp,
                                                int* __restrict__ bsum, int n) {
    __shared__ int s[1024];
    int i = blockIdx.x * 1024 + threadIdx.x;
    int v = (i < n) ? cnt[i] : 0;
    s[threadIdx.x] = v;
    __syncthreads();
    for (int off = 1; off < 1024; off <<= 1) {
        int add = (threadIdx.x >= off) ? s[threadIdx.x - off] : 0;
        __syncthreads();
        s[threadIdx.x] += add;
        __syncthreads();
    }
    if (i < n) tmp[i] = s[threadIdx.x];
    if (threadIdx.x == 1023) bsum[blockIdx.x] = s[1023];
}

// wave-parallel exclusive scan of up to 64 block sums
__global__ __launch_bounds__(64) void k_scan2(int* __restrict__ bsum, int nb) {
    int lane = threadIdx.x;
    int v = (lane < nb) ? bsum[lane] : 0;
    int orig = v;
    for (int off = 1; off < 64; off <<= 1) {
        int t = __shfl_up(v, off, 64);
        if (lane >= off) v += t;
    }
    if (lane < nb) bsum[lane] = v - orig;   // exclusive prefix
}

__global__ void k_scan3(const int* __restrict__ cnt, const int* __restrict__ tmp,
                        const int* __restrict__ bsum, int* __restrict__ rowptr,
                        int* __restrict__ cur, float* __restrict__ dinv, int n, int e) {
    int i = blockIdx.x * blockDim.x + threadIdx.x;
    if (i < n) {
        int excl = tmp[i] - cnt[i] + bsum[i >> 10];
        rowptr[i] = excl;
        cur[i] = excl;
        dinv[i] = 1.0f / sqrtf((float)(cnt[i] + 1));  // +1 self loop
        if (i == 0) rowptr[n] = e;
    }
}

__global__ void k_scatter(const int* __restrict__ ei, int* __restrict__ cur,
                          int* __restrict__ csrc, int2* __restrict__ cde, int e) {
    int i = blockIdx.x * blockDim.x + threadIdx.x;
    if (i < e) {
        int s = ei[i];
        int d = ei[e + i];
        int p = atomicAdd(&cur[d], 1);
        csrc[p] = s;
        cde[p] = make_int2(d, i);
    }
}

// ---------------- node GEMM: T = (A @ W) * dinv[row]  (W is [K,64]) ----------------

template <int K>
__global__ __launch_bounds__(256) void k_gemm_node(const float* __restrict__ A,
                                                   const float* __restrict__ W,
                                                   const float* __restrict__ dinv,
                                                   float* __restrict__ T,
                                                   int n, int npw) {
    int lane = threadIdx.x & 63;
    int w = threadIdx.x >> 6;
    float wr[K];
#pragma unroll
    for (int k = 0; k < K; ++k) wr[k] = W[k * 64 + lane];
    int gw = blockIdx.x * 4 + w;
    int n0 = gw * npw;
    int n1 = n0 + npw; if (n1 > n) n1 = n;
#pragma unroll 1
    for (int i = n0; i < n1; ++i) {
        float a0 = A[(size_t)i * K + lane];
        float a1 = 0.f;
        if (K == 128) a1 = A[(size_t)i * K + 64 + lane];
        float acc = 0.f;
#pragma unroll
        for (int k = 0; k < 64; ++k) acc = fmaf(rlanef(a0, k), wr[k], acc);
        if (K == 128) {
#pragma unroll
            for (int k = 0; k < 64; ++k) acc = fmaf(rlanef(a1, k), wr[64 + k], acc);
        }
        T[(size_t)i * 64 + lane] = acc * dinv[i];
    }
}

// uv GEMM: ut = h @ Wm1[0:64], vt = h @ Wm1[64:128] + bm1   (h = h2, [n][64])
__global__ __launch_bounds__(256) void k_gemm_uv(const float* __restrict__ Hm,
                                                 const float* __restrict__ Wm1,
                                                 const float* __restrict__ bm1,
                                                 float* __restrict__ ut,
                                                 float* __restrict__ vt,
                                                 int n, int npw) {
    int lane = threadIdx.x & 63;
    int w = threadIdx.x >> 6;
    float wu[64], wv[64];
#pragma unroll
    for (int k = 0; k < 64; ++k) wu[k] = Wm1[k * 64 + lane];
#pragma unroll
    for (int k = 0; k < 64; ++k) wv[k] = Wm1[(64 + k) * 64 + lane];
    float bv = bm1[lane];
    int gw = blockIdx.x * 4 + w;
    int n0 = gw * npw;
    int n1 = n0 + npw; if (n1 > n) n1 = n;
#pragma unroll 1
    for (int i = n0; i < n1; ++i) {
        float a0 = Hm[(size_t)i * 64 + lane];
        float au = 0.f, av = 0.f;
#pragma unroll
        for (int k = 0; k < 64; ++k) {
            float hb = rlanef(a0, k);
            au = fmaf(hb, wu[k], au);
            av = fmaf(hb, wv[k], av);
        }
        ut[(size_t)i * 64 + lane] = au;
        vt[(size_t)i * 64 + lane] = av + bv;
    }
}

// ---------------- GCN aggregation, float4 gather core ----------------
// lane = (g = lane>>4, c4 = lane&15). 4 neighbor rows in flight per iter,
// each as 16 lanes x float4 (full 256-B row). Cross-group shfl_xor reduce.

__device__ __forceinline__ float4 agg_gather(const float* __restrict__ T,
                                             const int* __restrict__ rowptr,
                                             const int* __restrict__ csrc,
                                             float dn, float4 b4,
                                             int nid, int g, int c4) {
    float4 acc = make_float4(0.f, 0.f, 0.f, 0.f);
    if (g == 0) {
        acc = *(const float4*)(T + (size_t)nid * 64 + 4 * c4);   // self loop
    }
    int r0 = rowptr[nid], r1 = rowptr[nid + 1];
#pragma unroll 1
    for (int p = r0 + g; p < r1; p += 4) {
        int s = csrc[p];
        float4 t = *(const float4*)(T + (size_t)s * 64 + 4 * c4);
        acc.x += t.x; acc.y += t.y; acc.z += t.z; acc.w += t.w;
    }
    acc.x += __shfl_xor(acc.x, 16, 64); acc.y += __shfl_xor(acc.y, 16, 64);
    acc.z += __shfl_xor(acc.z, 16, 64); acc.w += __shfl_xor(acc.w, 16, 64);
    acc.x += __shfl_xor(acc.x, 32, 64); acc.y += __shfl_xor(acc.y, 32, 64);
    acc.z += __shfl_xor(acc.z, 32, 64); acc.w += __shfl_xor(acc.w, 32, 64);
    float4 h;
    h.x = fmaxf(fmaf(dn, acc.x, b4.x), 0.f);
    h.y = fmaxf(fmaf(dn, acc.y, b4.y), 0.f);
    h.z = fmaxf(fmaf(dn, acc.z, b4.z), 0.f);
    h.w = fmaxf(fmaf(dn, acc.w, b4.w), 0.f);
    return h;
}

// layer-1 agg with fused layer-2 GEMM epilogue: T2 = (h1 @ W2) * dinv, h1 in regs only
__global__ __launch_bounds__(256) void k_agg_l1(const float* __restrict__ T,
                                                const int* __restrict__ rowptr,
                                                const int* __restrict__ csrc,
                                                const float* __restrict__ dinv,
                                                const float* __restrict__ bias,
                                                const float* __restrict__ W2,
                                                float* __restrict__ T2,
                                                int n, int npw) {
    int lane = threadIdx.x & 63;
    int w = threadIdx.x >> 6;
    int g = lane >> 4, c4 = lane & 15;
    float wr[64];
#pragma unroll
    for (int k = 0; k < 64; ++k) wr[k] = W2[k * 64 + lane];
    float4 b4 = ((const float4*)bias)[c4];
    int gw = blockIdx.x * 4 + w;
    int n0 = gw * npw;
    int n1 = n0 + npw; if (n1 > n) n1 = n;
#pragma unroll 1
    for (int nid = n0; nid < n1; ++nid) {
        float dn = dinv[nid];
        float4 h = agg_gather(T, rowptr, csrc, dn, b4, nid, g, c4);
        float acc2 = 0.f;
#pragma unroll
        for (int q = 0; q < 16; ++q) {
            acc2 = fmaf(rlanef(h.x, q), wr[4 * q + 0], acc2);
            acc2 = fmaf(rlanef(h.y, q), wr[4 * q + 1], acc2);
            acc2 = fmaf(rlanef(h.z, q), wr[4 * q + 2], acc2);
            acc2 = fmaf(rlanef(h.w, q), wr[4 * q + 3], acc2);
        }
        T2[(size_t)nid * 64 + lane] = acc2 * dn;
    }
}

// layer-2 agg: writes h2
__global__ __launch_bounds__(256) void k_agg_l2(const float* __restrict__ T,
                                                const int* __restrict__ rowptr,
                                                const int* __restrict__ csrc,
                                                const float* __restrict__ dinv,
                                                const float* __restrict__ bias,
                                                float* __restrict__ H,
                                                int n, int npw) {
    int lane = threadIdx.x & 63;
    int w = threadIdx.x >> 6;
    int g = lane >> 4, c4 = lane & 15;
    float4 b4 = ((const float4*)bias)[c4];
    int gw = blockIdx.x * 4 + w;
    int n0 = gw * npw;
    int n1 = n0 + npw; if (n1 > n) n1 = n;
#pragma unroll 1
    for (int nid = n0; nid < n1; ++nid) {
        float dn = dinv[nid];
        float4 h = agg_gather(T, rowptr, csrc, dn, b4, nid, g, c4);
        if (g == 0) *(float4*)(H + (size_t)nid * 64 + 4 * c4) = h;
    }
}

// ---------------- edge MLP (CSR order, u/v precomputed) ----------------

#define RELUADD4(zq, uq, vq) \
    zq.x = fmaxf(uq.x + vq.x, 0.f); zq.y = fmaxf(uq.y + vq.y, 0.f); \
    zq.z = fmaxf(uq.z + vq.z, 0.f); zq.w = fmaxf(uq.w + vq.w, 0.f);

#define S2Q(zs, j) { \
    const float* w2 = Wm2 + (size_t)(j) * 16; \
    o0.x = fmaf(zs, w2[0],  o0.x);  o0.y = fmaf(zs, w2[1],  o0.y); \
    o0.z = fmaf(zs, w2[2],  o0.z);  o0.w = fmaf(zs, w2[3],  o0.w); \
    o1.x = fmaf(zs, w2[4],  o1.x);  o1.y = fmaf(zs, w2[5],  o1.y); \
    o1.z = fmaf(zs, w2[6],  o1.z);  o1.w = fmaf(zs, w2[7],  o1.w); \
    o2.x = fmaf(zs, w2[8],  o2.x);  o2.y = fmaf(zs, w2[9],  o2.y); \
    o2.z = fmaf(zs, w2[10], o2.z);  o2.w = fmaf(zs, w2[11], o2.w); \
    o3.x = fmaf(zs, w2[12], o3.x);  o3.y = fmaf(zs, w2[13], o3.y); \
    o3.z = fmaf(zs, w2[14], o3.z);  o3.w = fmaf(zs, w2[15], o3.w); }

__global__ __launch_bounds__(256, 4) void k_mlp(const float* __restrict__ ut,
                                                const float* __restrict__ vt,
                                                const int* __restrict__ csrc,
                                                const int2* __restrict__ cde,
                                                const float* __restrict__ Wm2,  // [64][16]
                                                const float* __restrict__ bm2,
                                                float* __restrict__ out,
                                                int e) {
    int p = blockIdx.x * 256 + threadIdx.x;
    bool ok = p < e;
    int idx = ok ? p : 0;
    int r = csrc[idx];
    int2 cv = cde[idx];
    int c  = cv.x;
    int eo = cv.y;

    const float4* uq = (const float4*)(ut + (size_t)r * 64);
    const float4* vq = (const float4*)(vt + (size_t)c * 64);

    float4 u0 = uq[0],  u1 = uq[1],  u2 = uq[2],  u3 = uq[3];
    float4 u4 = uq[4],  u5 = uq[5],  u6 = uq[6],  u7 = uq[7];
    float4 u8 = uq[8],  u9 = uq[9],  u10 = uq[10], u11 = uq[11];
    float4 u12 = uq[12], u13 = uq[13], u14 = uq[14], u15 = uq[15];
    float4 v0 = vq[0],  v1 = vq[1],  v2 = vq[2],  v3 = vq[3];
    float4 v4 = vq[4],  v5 = vq[5],  v6 = vq[6],  v7 = vq[7];
    float4 v8 = vq[8],  v9 = vq[9],  v10 = vq[10], v11 = vq[11];
    float4 v12 = vq[12], v13 = vq[13], v14 = vq[14], v15 = vq[15];

    float4 z0, z1, z2, z3, z4, z5, z6, z7, z8, z9, z10, z11, z12, z13, z14, z15;
    RELUADD4(z0, u0, v0)    RELUADD4(z1, u1, v1)    RELUADD4(z2, u2, v2)    RELUADD4(z3, u3, v3)
    RELUADD4(z4, u4, v4)    RELUADD4(z5, u5, v5)    RELUADD4(z6, u6, v6)    RELUADD4(z7, u7, v7)
    RELUADD4(z8, u8, v8)    RELUADD4(z9, u9, v9)    RELUADD4(z10, u10, v10) RELUADD4(z11, u11, v11)
    RELUADD4(z12, u12, v12) RELUADD4(z13, u13, v13) RELUADD4(z14, u14, v14) RELUADD4(z15, u15, v15)

    const float4* b2q = (const float4*)bm2;
    float4 o0 = b2q[0], o1 = b2q[1], o2 = b2q[2], o3 = b2q[3];

    S2Q(z0.x, 0)   S2Q(z0.y, 1)   S2Q(z0.z, 2)   S2Q(z0.w, 3)
    S2Q(z1.x, 4)   S2Q(z1.y, 5)   S2Q(z1.z, 6)   S2Q(z1.w, 7)
    S2Q(z2.x, 8)   S2Q(z2.y, 9)   S2Q(z2.z, 10)  S2Q(z2.w, 11)
    S2Q(z3.x, 12)  S2Q(z3.y, 13)  S2Q(z3.z, 14)  S2Q(z3.w, 15)
    S2Q(z4.x, 16)  S2Q(z4.y, 17)  S2Q(z4.z, 18)  S2Q(z4.w, 19)
    S2Q(z5.x, 20)  S2Q(z5.y, 21)  S2Q(z5.z, 22)  S2Q(z5.w, 23)
    S2Q(z6.x, 24)  S2Q(z6.y, 25)  S2Q(z6.z, 26)  S2Q(z6.w, 27)
    S2Q(z7.x, 28)  S2Q(z7.y, 29)  S2Q(z7.z, 30)  S2Q(z7.w, 31)
    S2Q(z8.x, 32)  S2Q(z8.y, 33)  S2Q(z8.z, 34)  S2Q(z8.w, 35)
    S2Q(z9.x, 36)  S2Q(z9.y, 37)  S2Q(z9.z, 38)  S2Q(z9.w, 39)
    S2Q(z10.x, 40) S2Q(z10.y, 41) S2Q(z10.z, 42) S2Q(z10.w, 43)
    S2Q(z11.x, 44) S2Q(z11.y, 45) S2Q(z11.z, 46) S2Q(z11.w, 47)
    S2Q(z12.x, 48) S2Q(z12.y, 49) S2Q(z12.z, 50) S2Q(z12.w, 51)
    S2Q(z13.x, 52) S2Q(z13.y, 53) S2Q(z13.z, 54) S2Q(z13.w, 55)
    S2Q(z14.x, 56) S2Q(z14.y, 57) S2Q(z14.z, 58) S2Q(z14.w, 59)
    S2Q(z15.x, 60) S2Q(z15.y, 61) S2Q(z15.z, 62) S2Q(z15.w, 63)

    if (ok) {
        float4* op = (float4*)(out + (size_t)eo * 16);
        op[0] = o0; op[1] = o1; op[2] = o2; op[3] = o3;
    }
}

// ---------------- launch ----------------

extern "C" void kernel_launch(void* const* d_in, const int* in_sizes, int n_in,
                              void* d_out, int out_size, void* d_ws, size_t ws_size,
                              hipStream_t stream) {
    const float* x   = (const float*)d_in[0];
    const int*   ei  = (const int*)d_in[1];
    const float* W1  = (const float*)d_in[2];
    const float* b1  = (const float*)d_in[3];
    const float* W2  = (const float*)d_in[4];
    const float* b2  = (const float*)d_in[5];
    const float* Wm1 = (const float*)d_in[6];
    const float* bm1 = (const float*)d_in[7];
    const float* Wm2 = (const float*)d_in[8];
    const float* bm2 = (const float*)d_in[9];
    float* out = (float*)d_out;

    int n = in_sizes[0] / IN_C;       // 50000
    int e = in_sizes[1] / 2;          // 800000

    // workspace layout (16B-aligned chunks)
    char* w = (char*)d_ws;
    int* cnt    = (int*)w;                 w += (size_t)n * 4;
    int* tmp    = (int*)w;                 w += (size_t)n * 4;
    int* bsum   = (int*)w;                 w += 256 * 4;
    int* rowptr = (int*)w;                 w += (size_t)(n + 4) * 4;
    int* cur    = (int*)w;                 w += (size_t)n * 4;
    float* dinv = (float*)w;               w += (size_t)n * 4;
    int* csrc   = (int*)w;                 w += (size_t)e * 4;
    int2* cde   = (int2*)w;                w += (size_t)e * 8;
    float* t1   = (float*)w;               w += (size_t)n * HID * 4;
    float* t2   = (float*)w;               w += (size_t)n * HID * 4;
    float* h2   = (float*)w;               w += (size_t)n * HID * 4;
    float* ut   = t1;   // reuse: t1 dead after agg_l1
    float* vt   = t2;   // reuse: t2 dead after agg_l2

    int nb_n256 = (n + 255) / 256;
    int nb_e256 = (e + 255) / 256;
    int nb_scan = (n + 1023) / 1024;

    k_init_cnt<<<nb_n256, 256, 0, stream>>>(cnt, n);
    k_count<<<nb_e256, 256, 0, stream>>>(ei, cnt, e);
    k_scan1<<<nb_scan, 1024, 0, stream>>>(cnt, tmp, bsum, n);
    k_scan2<<<1, 64, 0, stream>>>(bsum, nb_scan);
    k_scan3<<<nb_n256, 256, 0, stream>>>(cnt, tmp, bsum, rowptr, cur, dinv, n, e);
    k_scatter<<<nb_e256, 256, 0, stream>>>(ei, cur, csrc, cde, e);

    const int NPW = 8;                               // nodes per wave (gemm)
    int nwaves = (n + NPW - 1) / NPW;
    int nb_gemm = (nwaves + 3) / 4;
    const int NPB = 8;                               // nodes per wave (agg)
    int nb_agg = (n + 4 * NPB - 1) / (4 * NPB);

    // layer 1 transform
    k_gemm_node<IN_C><<<nb_gemm, 256, 0, stream>>>(x, W1, dinv, t1, n, NPW);
    // layer-1 agg + fused layer-2 transform
    k_agg_l1<<<nb_agg, 256, 0, stream>>>(t1, rowptr, csrc, dinv, b1, W2, t2, n, NPB);
    // layer-2 agg
    k_agg_l2<<<nb_agg, 256, 0, stream>>>(t2, rowptr, csrc, dinv, b2, h2, n, NPB);
    // per-node u/v for the edge MLP
    k_gemm_uv<<<nb_gemm, 256, 0, stream>>>(h2, Wm1, bm1, ut, vt, n, NPW);
    // edge MLP in CSR order
    int nb_mlp = (e + 255) / 256;
    k_mlp<<<nb_mlp, 256, 0, stream>>>(ut, vt, csrc, cde, Wm2, bm2, out, e);
}